// Round 3
// baseline (134.575 us; speedup 1.0000x reference)
//
#include <hip/hip_runtime.h>
#include <hip/hip_bf16.h>
#include <cstdint>

// DenseMRConv: out = concat([x, max_k(x[idx[n,k]] - x[n])]) @ W + b
// N=100000, K=32, d=64, d_out=64.
//
// R8: gather concurrency via global_load_lds DMA (no VGPR destinations -> the
// compiler cannot collapse the window; R6/R7 both failed at VGPR=40 with ~0.5
// loads in flight per wave). Per wave: 4 rounds x 4 DMA instrs (1KB each, 8
// rows), double-buffered 2x4KB, counted vmcnt(4) waits. Readback ds_read_b128
// has bank-group == e -> even 8-per-group, conflict-free. otile dropped
// (direct coalesced stores) so LDS = 40.2KB -> 4 blocks/CU.
// Kept: max-first, packed-u16 order-preserving-key max, prebuilt W B-frags.

typedef __attribute__((ext_vector_type(8))) short short8;
typedef __attribute__((ext_vector_type(4))) float f4;
typedef __attribute__((ext_vector_type(8))) unsigned short u16x8;
typedef __attribute__((ext_vector_type(4))) unsigned int u32x4;

#define TILE 16
#define ROWS 168   // padded h row stride in bf16 elems (336 B, 16B-aligned)

__device__ __forceinline__ unsigned short f2bf(float f) {
  unsigned int u = __builtin_bit_cast(unsigned int, f);
  u += 0x7fffu + ((u >> 16) & 1u);          // round-to-nearest-even
  return (unsigned short)(u >> 16);
}
__device__ __forceinline__ unsigned int pack2(float a, float b) {
  return (unsigned int)f2bf(a) | ((unsigned int)f2bf(b) << 16);
}
__device__ __forceinline__ float bflo(unsigned int u) {
  return __builtin_bit_cast(float, u << 16);
}
__device__ __forceinline__ float bfhi(unsigned int u) {
  return __builtin_bit_cast(float, u & 0xffff0000u);
}
// bf16 -> unsigned-monotone key, per 16-bit half: sign ? ~u : u|0x8000
__device__ __forceinline__ unsigned int key2(unsigned int u) {
  unsigned int s = u & 0x80008000u;
  unsigned int m = (s >> 15) * 0x7fffu;            // 0x7fff where sign set
  return u ^ (0x80008000u | m);                    // ^0xffff (neg) / ^0x8000 (pos)
}
// inverse: key -> raw bf16 bits
__device__ __forceinline__ unsigned int unkey2(unsigned int k) {
  unsigned int s = k & 0x80008000u;
  unsigned int m = ((s >> 15) ^ 0x00010001u) * 0x7fffu; // 0x7fff where key-sign clear
  return k ^ (0x80008000u | m);
}
__device__ __forceinline__ u16x8 pmax8(u16x8 a, u16x8 b) {
  return __builtin_elementwise_max(a, b);          // 4x v_pk_max_u16
}
// global -> LDS DMA, 16B per lane. gptr is PER-LANE; lptr is wave-uniform
// base, HW writes at base + lane*16.
__device__ __forceinline__ void gl16(const void* g, void* l) {
  __builtin_amdgcn_global_load_lds(
      (const __attribute__((address_space(1))) void*)g,
      (__attribute__((address_space(3))) void*)l, 16, 0, 0);
}

#define WAITV4 do { asm volatile("s_waitcnt vmcnt(4)" ::: "memory"); \
                    __builtin_amdgcn_sched_barrier(0); } while (0)
#define WAITV0 do { asm volatile("s_waitcnt vmcnt(0)" ::: "memory"); \
                    __builtin_amdgcn_sched_barrier(0); } while (0)
#define WAITL0 do { asm volatile("s_waitcnt lgkmcnt(0)" ::: "memory"); \
                    __builtin_amdgcn_sched_barrier(0); } while (0)

// ---- pass 1: x -> keyed bf16 copy (blocks [0,nxb)), W -> MFMA B-frags (block nxb)
__global__ __launch_bounds__(256)
void convert_kernel(const float* __restrict__ x, unsigned int* __restrict__ xbf,
                    const float* __restrict__ W, unsigned short* __restrict__ wf,
                    int n8, int nxb) {
  if ((int)blockIdx.x < nxb) {
    int i = blockIdx.x * 256 + threadIdx.x;
    if (i >= n8) return;
    const f4* p = (const f4*)x + (size_t)i * 2;
    f4 a = __builtin_nontemporal_load(p);
    f4 b = __builtin_nontemporal_load(p + 1);
    u32x4 w;
    w.x = key2(pack2(a.x, a.y)); w.y = key2(pack2(a.z, a.w));
    w.z = key2(pack2(b.x, b.y)); w.w = key2(pack2(b.z, b.w));
    ((u32x4*)xbf)[i] = w;                    // regular store: keep L2/L3-resident
  } else {
    #pragma unroll
    for (int q = 0; q < 4; ++q) {
      int idx = threadIdx.x * 4 + q;
      int wv = idx >> 8, ks = (idx >> 6) & 3, l = idx & 63;
      int c = l & 15, g = l >> 4;
      short8 v;
      #pragma unroll
      for (int j = 0; j < 8; ++j)
        v[j] = (short)f2bf(W[(ks * 32 + g * 8 + j) * 64 + wv * 16 + c]);
      *(short8*)(wf + (size_t)idx * 8) = v;
    }
  }
}

// ---- pass 2: DMA-gather + packed-key max + MFMA GEMM. One block / 16 nodes.
__global__ __launch_bounds__(256, 4)
void mrconv4_kernel(const unsigned int* __restrict__ xbf,  // keyed bf16, 2/uint
                    const unsigned short* __restrict__ wf, // prebuilt B-frags
                    const int* __restrict__ ei,
                    const float* __restrict__ bias,
                    float* __restrict__ out,
                    int n_tiles)
{
  // per-wave staging: [wave][buf][4KB]: buf holds 4 subtiles (one per node),
  // each 1KB = 8 rows x 128B, row-major (DMA writes lane-linear).
  __shared__ __align__(16) unsigned short stg[4][2][2048];
  // eis3[s(8)][t(16)][r(4)]: index of neighbor (8r+s) of node t
  __shared__ __align__(16) int eis3[512];
  __shared__ __align__(16) unsigned short hs[TILE * ROWS];

  const int tid  = threadIdx.x;
  const int wv   = tid >> 6;
  const int lane = tid & 63;
  const int c  = lane & 15;        // MFMA col selector (Phase B)
  const int g  = lane >> 4;        // MFMA quad group  (Phase B)
  const int t2 = lane >> 4;        // reduce: which of this wave's 4 nodes
  const int rr = (lane >> 3) & 1;  // reduce: neighbor sub-half
  const int e  = lane & 7;         // 16B feature chunk
  const int s  = lane >> 3;        // staging: row slot within DMA instr (0..7)

  const int node0 = blockIdx.x * TILE;
  const int t = wv * 4 + t2;       // node row within tile

  // ---- stage indices: ei int32[16][32] per tile, re-laid into eis3.
  {
    long long ev = __builtin_nontemporal_load(
        (const long long*)ei + (size_t)node0 * 16 + tid);
    const int ts = tid >> 4, qs = tid & 15;
    const int k0 = qs * 2, k1 = qs * 2 + 1;
    eis3[((k0 & 7) * 16 + ts) * 4 + (k0 >> 3)] = (int)ev;
    eis3[((k1 & 7) * 16 + ts) * 4 + (k1 >> 3)] = (int)(ev >> 32);
  }

  // own row + B-frags issued BEFORE the barrier (barrier drains vmcnt, so the
  // counted waits below only see our DMA ops + any compiler extras, which the
  // oldest-first vmcnt retirement makes safe anyway).
  const char* __restrict__ xb = (const char*)xbf;
  const unsigned co = (unsigned)e * 16u;
  const u16x8 xrk = *(const u16x8*)(xb + (size_t)((unsigned)(node0 + t) * 128u + co));
  short8 bfrag[4];
  #pragma unroll
  for (int ks = 0; ks < 4; ++ks)
    bfrag[ks] = *(const short8*)(wf + (size_t)((wv * 4 + ks) * 64 + lane) * 8);
  __syncthreads();

  // per-lane neighbor indices: q_n[r] = ei[wv*4+n][8r+s]
  const int4 q0 = *(const int4*)&eis3[(s * 16 + wv * 4 + 0) * 4];
  const int4 q1 = *(const int4*)&eis3[(s * 16 + wv * 4 + 1) * 4];
  const int4 q2 = *(const int4*)&eis3[(s * 16 + wv * 4 + 2) * 4];
  const int4 q3 = *(const int4*)&eis3[(s * 16 + wv * 4 + 3) * 4];

  unsigned short* const sw0 = &stg[wv][0][0];
  unsigned short* const sw1 = &stg[wv][1][0];

  // ISSUE one round (4 DMA instrs, one per node) into a buffer.
#define ISS(I0, I1, I2, I3, SW)                                   \
  gl16(xb + ((unsigned)(I0) * 128u + co), (SW));                  \
  gl16(xb + ((unsigned)(I1) * 128u + co), (SW) + 512);            \
  gl16(xb + ((unsigned)(I2) * 128u + co), (SW) + 1024);           \
  gl16(xb + ((unsigned)(I3) * 128u + co), (SW) + 1536)

  // reduce base for this lane: subtile t2, rows rr*4+j, chunk e (ushort units)
  const unsigned rbase = (unsigned)t2 * 512 + (unsigned)rr * 256 + (unsigned)e * 8;

  u16x8 ka, kb;
#define RED_INIT(SW) {                                            \
    const u16x8 v0 = *(const u16x8*)((SW) + rbase);               \
    const u16x8 v1 = *(const u16x8*)((SW) + rbase + 64);          \
    const u16x8 v2 = *(const u16x8*)((SW) + rbase + 128);         \
    const u16x8 v3 = *(const u16x8*)((SW) + rbase + 192);         \
    ka = pmax8(v0, v2); kb = pmax8(v1, v3); }
#define RED_ACC(SW) {                                             \
    const u16x8 v0 = *(const u16x8*)((SW) + rbase);               \
    const u16x8 v1 = *(const u16x8*)((SW) + rbase + 64);          \
    const u16x8 v2 = *(const u16x8*)((SW) + rbase + 128);         \
    const u16x8 v3 = *(const u16x8*)((SW) + rbase + 192);         \
    ka = pmax8(ka, pmax8(v0, v2)); kb = pmax8(kb, pmax8(v1, v3)); }

  // pipeline: r0->A, r1->B | wait4, red A | r2->A | wait4, red B | r3->B |
  //           wait4, red A | wait0, red B
  ISS(q0.x, q1.x, q2.x, q3.x, sw0);
  ISS(q0.y, q1.y, q2.y, q3.y, sw1);
  WAITV4;
  RED_INIT(sw0);
  WAITL0;                              // ds_reads of sw0 retired before rewrite
  ISS(q0.z, q1.z, q2.z, q3.z, sw0);
  WAITV4;
  RED_ACC(sw1);
  WAITL0;
  ISS(q0.w, q1.w, q2.w, q3.w, sw1);
  WAITV4;
  RED_ACC(sw0);
  WAITV0;
  RED_ACC(sw1);

  u16x8 km = pmax8(ka, kb);

  // merge the rr-pair (lane bit 3): 4 dword shuffles + 1 packed max
  u32x4 k4 = __builtin_bit_cast(u32x4, km);
  u32x4 s4;
  s4.x = (unsigned)__shfl_xor((int)k4.x, 8);
  s4.y = (unsigned)__shfl_xor((int)k4.y, 8);
  s4.z = (unsigned)__shfl_xor((int)k4.z, 8);
  s4.w = (unsigned)__shfl_xor((int)k4.w, 8);
  km = pmax8(km, __builtin_bit_cast(u16x8, s4));
  k4 = __builtin_bit_cast(u32x4, km);

  // un-key own row once (needed by both halves)
  const u32x4 xr4 = __builtin_bit_cast(u32x4, xrk);
  u32x4 xw;
  xw.x = unkey2(xr4.x); xw.y = unkey2(xr4.y);
  xw.z = unkey2(xr4.z); xw.w = unkey2(xr4.w);

  if (rr == 0) {           // diff half: (max x_j) - x_i, in f32 then RNE pack
    const unsigned m0 = unkey2(k4.x), m1 = unkey2(k4.y);
    const unsigned m2 = unkey2(k4.z), m3 = unkey2(k4.w);
    u32x4 w;
    w.x = pack2(bflo(m0) - bflo(xw.x), bfhi(m0) - bfhi(xw.x));
    w.y = pack2(bflo(m1) - bflo(xw.y), bfhi(m1) - bfhi(xw.y));
    w.z = pack2(bflo(m2) - bflo(xw.z), bfhi(m2) - bfhi(xw.z));
    w.w = pack2(bflo(m3) - bflo(xw.w), bfhi(m3) - bfhi(xw.w));
    *(u32x4*)(hs + t * ROWS + 64 + e * 8) = w;
  } else {                 // x half: raw bf16 copy
    *(u32x4*)(hs + t * ROWS + e * 8) = xw;
  }
  __syncthreads();

  // ---- Phase B: wave wv computes C[:, wv*16 : wv*16+16] via 4 MFMAs.
  f4 acc = {0.f, 0.f, 0.f, 0.f};
  #pragma unroll
  for (int ks = 0; ks < 4; ++ks) {
    // A layout: lane holds A[m=l&15][k=(l>>4)*8+j]
    short8 a = *(const short8*)(hs + c * ROWS + ks * 32 + g * 8);
    acc = __builtin_amdgcn_mfma_f32_16x16x32_bf16(a, bfrag[ks], acc, 0, 0, 0);
  }

  // ---- Epilogue: C layout col=lane&15, row=(lane>>4)*4+reg [m89-verified].
  // Direct stores: per instr, lanes cover 4 rows x 64B contiguous chunks.
  const float bb = bias[wv * 16 + c];
  #pragma unroll
  for (int j = 0; j < 4; ++j)
    __builtin_nontemporal_store(acc[j] + bb,
        out + (size_t)(node0 + g * 4 + j) * 64 + wv * 16 + c);
#undef ISS
#undef RED_INIT
#undef RED_ACC
}

// ---- fallback (ws too small): R2's proven fp32 kernel
#define FWPB 4
#define FROWS 160
__global__ __launch_bounds__(256, 4)
void mrconv_fp32_kernel(const float* __restrict__ x,
                        const int* __restrict__ ei,
                        const float* __restrict__ W,
                        const float* __restrict__ bias,
                        float* __restrict__ out,
                        int n_tiles)
{
  __shared__ __align__(16) unsigned short hsf[FWPB][TILE * FROWS];
  const int wave = threadIdx.x >> 6;
  const int lane = threadIdx.x & 63;
  const int c = lane & 15;
  const int g = lane >> 4;

  short8 bfrag[4][4];
  #pragma unroll
  for (int ks = 0; ks < 4; ++ks) {
    #pragma unroll
    for (int nt = 0; nt < 4; ++nt) {
      short8 v;
      #pragma unroll
      for (int j = 0; j < 8; ++j) {
        int k = ks * 32 + g * 8 + j;
        v[j] = (short)f2bf(W[k * 64 + nt * 16 + c]);
      }
      bfrag[ks][nt] = v;
    }
  }

  const int tile = blockIdx.x * FWPB + wave;
  if (tile >= n_tiles) return;
  const int node0 = tile * TILE;
  unsigned short* hrow = &hsf[wave][0];

  #pragma unroll 2
  for (int t = 0; t < TILE; ++t) {
    const int n = node0 + t;
    const f4 xi = *(const f4*)(x + (size_t)n * 64 + 4 * c);
    f4 m = { -3.4e38f, -3.4e38f, -3.4e38f, -3.4e38f };
    #pragma unroll
    for (int it = 0; it < 8; ++it) {
      const int j = ei[(size_t)n * 32 + it * 4 + g];
      const f4 xj = *(const f4*)(x + (size_t)j * 64 + 4 * c);
      m.x = fmaxf(m.x, xj.x - xi.x);
      m.y = fmaxf(m.y, xj.y - xi.y);
      m.z = fmaxf(m.z, xj.z - xi.z);
      m.w = fmaxf(m.w, xj.w - xi.w);
    }
    m.x = fmaxf(m.x, __shfl_xor(m.x, 16));
    m.y = fmaxf(m.y, __shfl_xor(m.y, 16));
    m.z = fmaxf(m.z, __shfl_xor(m.z, 16));
    m.w = fmaxf(m.w, __shfl_xor(m.w, 16));
    m.x = fmaxf(m.x, __shfl_xor(m.x, 32));
    m.y = fmaxf(m.y, __shfl_xor(m.y, 32));
    m.z = fmaxf(m.z, __shfl_xor(m.z, 32));
    m.w = fmaxf(m.w, __shfl_xor(m.w, 32));
    if (g == 0) {
      ushort4 p;
      p.x = f2bf(xi.x); p.y = f2bf(xi.y); p.z = f2bf(xi.z); p.w = f2bf(xi.w);
      *(ushort4*)(hrow + t * FROWS + 4 * c) = p;
    } else if (g == 1) {
      ushort4 p;
      p.x = f2bf(m.x); p.y = f2bf(m.y); p.z = f2bf(m.z); p.w = f2bf(m.w);
      *(ushort4*)(hrow + t * FROWS + 64 + 4 * c) = p;
    }
  }
  __asm__ volatile("s_waitcnt lgkmcnt(0)" ::: "memory");

  f4 acc[4] = {{0.f,0.f,0.f,0.f},{0.f,0.f,0.f,0.f},{0.f,0.f,0.f,0.f},{0.f,0.f,0.f,0.f}};
  #pragma unroll
  for (int ks = 0; ks < 4; ++ks) {
    short8 a = *(const short8*)(hrow + c * FROWS + ks * 32 + g * 8);
    #pragma unroll
    for (int nt = 0; nt < 4; ++nt)
      acc[nt] = __builtin_amdgcn_mfma_f32_16x16x32_bf16(a, bfrag[ks][nt], acc[nt], 0, 0, 0);
  }
  const int rbase = node0 + g * 4;
  #pragma unroll
  for (int nt = 0; nt < 4; ++nt) {
    const float bb = bias[nt * 16 + c];
    #pragma unroll
    for (int j = 0; j < 4; ++j)
      out[(size_t)(rbase + j) * 64 + nt * 16 + c] = acc[nt][j] + bb;
  }
}

extern "C" void kernel_launch(void* const* d_in, const int* in_sizes, int n_in,
                              void* d_out, int out_size, void* d_ws, size_t ws_size,
                              hipStream_t stream) {
  const float* x  = (const float*)d_in[0];
  const int*   ei = (const int*)d_in[1];     // int64 in reference -> int32 here
  const float* W  = (const float*)d_in[2];
  const float* b  = (const float*)d_in[3];
  float* out = (float*)d_out;

  const int N = in_sizes[0] / 64;            // 100000
  const int n_tiles = N / TILE;              // 6250

  const size_t xbf_bytes = (size_t)N * 64 * 2;   // 12.8 MB
  const size_t wf_bytes  = 1024 * 16;            // 16 KB of B-frags
  if (ws_size >= xbf_bytes + wf_bytes) {
    unsigned int*   xbf = (unsigned int*)d_ws;
    unsigned short* wf  = (unsigned short*)((char*)d_ws + xbf_bytes);
    const int n8  = N * 64 / 8;                  // 800000
    const int nxb = (n8 + 255) / 256;            // 3125
    hipLaunchKernelGGL(convert_kernel, dim3(nxb + 1), dim3(256), 0, stream,
                       x, xbf, W, wf, n8, nxb);
    hipLaunchKernelGGL(mrconv4_kernel, dim3(n_tiles), dim3(256), 0, stream,
                       xbf, wf, ei, b, out, n_tiles);
  } else {
    const int blocks = (n_tiles + FWPB - 1) / FWPB;
    hipLaunchKernelGGL(mrconv_fp32_kernel, dim3(blocks), dim3(256), 0, stream,
                       x, ei, W, b, out, n_tiles);
  }
}